// Round 1
// baseline (4846.676 us; speedup 1.0000x reference)
//
#include <hip/hip_runtime.h>
#include <hip/hip_bf16.h>

typedef unsigned short u16;
typedef unsigned int u32;
typedef __attribute__((ext_vector_type(4))) float f32x4;
typedef __attribute__((ext_vector_type(8))) short short8;
typedef __attribute__((ext_vector_type(8))) __bf16 bf16x8;

#define DI __device__ __forceinline__

constexpr int D    = 1024;
constexpr int NTOK = 2048;
constexpr int HD   = 64;
constexpr int NH   = 16;
constexpr int KVH  = 4;
constexpr int FF   = 2048;
constexpr int NE   = 8;
constexpr int CHUNK = 512;
constexpr int TCAP = 5120;   // padded expert-row capacity (4096 + 8*127 <= 5120)
constexpr int VOC  = 32000;

DI u16 f2bf(float f) {
    u32 u = __builtin_bit_cast(u32, f);
    return (u16)((u + 0x7FFFu + ((u >> 16) & 1u)) >> 16);
}
DI float bf2f(u16 b) { u32 u = ((u32)b) << 16; return __builtin_bit_cast(float, u); }

DI f32x4 MFMA(short8 a, short8 b, f32x4 c) {
    return __builtin_amdgcn_mfma_f32_16x16x32_bf16(
        __builtin_bit_cast(bf16x8, a), __builtin_bit_cast(bf16x8, b), c, 0, 0, 0);
}

// ---------------- small kernels ----------------

__global__ void zero32_k(u32* p, int n) {
    int i = blockIdx.x * blockDim.x + threadIdx.x;
    if (i < n) p[i] = 0u;
}

__global__ void embed_k(const int* __restrict__ ids, const float* __restrict__ W,
                        float* __restrict__ h) {
    int n = blockIdx.x;
    int d = threadIdx.x * 4;
    float4 v = *(const float4*)(W + (size_t)ids[n] * D + d);
    *(float4*)(h + (size_t)n * D + d) = v;
}

__global__ void rmsnorm_k(const float* __restrict__ h, const float* __restrict__ w,
                          float* __restrict__ of, u16* __restrict__ ohi, u16* __restrict__ olo) {
    int n = blockIdx.x;
    const float* row = h + (size_t)n * D;
    int d = threadIdx.x * 4;
    float4 v = *(const float4*)(row + d);
    float ss = v.x * v.x + v.y * v.y + v.z * v.z + v.w * v.w;
    for (int off = 32; off; off >>= 1) ss += __shfl_down(ss, off);
    __shared__ float sred[4];
    int wid = threadIdx.x >> 6;
    if ((threadIdx.x & 63) == 0) sred[wid] = ss;
    __syncthreads();
    float tot = sred[0] + sred[1] + sred[2] + sred[3];
    float scale = rsqrtf(tot / (float)D + 1e-6f);
    float4 wv = *(const float4*)(w + d);
    float o[4] = { v.x * wv.x * scale, v.y * wv.y * scale, v.z * wv.z * scale, v.w * wv.w * scale };
#pragma unroll
    for (int j = 0; j < 4; ++j) {
        size_t idx = (size_t)n * D + d + j;
        of[idx] = o[j];
        u16 hi = f2bf(o[j]);
        ohi[idx] = hi;
        olo[idx] = f2bf(o[j] - bf2f(hi));
    }
}

__global__ void ropetab_k(float* __restrict__ ct, float* __restrict__ st) {
    int i = blockIdx.x * 256 + threadIdx.x;
    if (i >= CHUNK * 32) return;
    int pos = i >> 5, fi = i & 31;
    float inv = powf(1.0e6f, -(float)(2 * fi) / 64.0f);
    float ang = (float)pos * inv;
    ct[i] = cosf(ang);
    st[i] = sinf(ang);
}

__global__ void rope_k(const float* __restrict__ qf, const float* __restrict__ kf,
                       const float* __restrict__ vf,
                       const float* __restrict__ ct, const float* __restrict__ st,
                       u16* __restrict__ qhi, u16* __restrict__ qlo,
                       u16* __restrict__ khi, u16* __restrict__ klo,
                       u16* __restrict__ vhi, u16* __restrict__ vlo) {
    int n = blockIdx.x;
    int pos = n & (CHUNK - 1);
    for (int i = threadIdx.x; i < 512; i += 256) {   // q: 16 heads * 32 pairs
        int pi = i & 31;
        float c = ct[pos * 32 + pi], s = st[pos * 32 + pi];
        size_t idx = (size_t)n * (NH * HD) + (i >> 5) * 64 + 2 * pi;
        float x1 = qf[idx], x2 = qf[idx + 1];
        float y1 = x1 * c - x2 * s;
        float y2 = x1 * s + x2 * c;
        u16 h1 = f2bf(y1); qhi[idx] = h1; qlo[idx] = f2bf(y1 - bf2f(h1));
        u16 h2 = f2bf(y2); qhi[idx + 1] = h2; qlo[idx + 1] = f2bf(y2 - bf2f(h2));
    }
    for (int i = threadIdx.x; i < 128; i += 256) {   // k: 4 kv heads * 32 pairs
        int pi = i & 31;
        float c = ct[pos * 32 + pi], s = st[pos * 32 + pi];
        size_t idx = (size_t)n * (KVH * HD) + (i >> 5) * 64 + 2 * pi;
        float x1 = kf[idx], x2 = kf[idx + 1];
        float y1 = x1 * c - x2 * s;
        float y2 = x1 * s + x2 * c;
        u16 h1 = f2bf(y1); khi[idx] = h1; klo[idx] = f2bf(y1 - bf2f(h1));
        u16 h2 = f2bf(y2); khi[idx + 1] = h2; klo[idx + 1] = f2bf(y2 - bf2f(h2));
    }
    for (int i = threadIdx.x; i < 256; i += 256) {   // v passthrough split
        size_t idx = (size_t)n * (KVH * HD) + i;
        float x = vf[idx];
        u16 h1 = f2bf(x); vhi[idx] = h1; vlo[idx] = f2bf(x - bf2f(h1));
    }
}

__global__ void router_k(const float* __restrict__ x, const float* __restrict__ rwl,
                         int l, int* __restrict__ topi, float* __restrict__ topw,
                         int* __restrict__ cnt, float* __restrict__ psum, float* __restrict__ fcnt) {
    int n = blockIdx.x;
    const float* row = x + (size_t)n * D;
    float acc[8] = {0, 0, 0, 0, 0, 0, 0, 0};
    for (int d = threadIdx.x; d < D; d += 256) {
        float xv = row[d];
#pragma unroll
        for (int e = 0; e < 8; ++e) acc[e] += xv * rwl[d * 8 + e];
    }
#pragma unroll
    for (int e = 0; e < 8; ++e)
        for (int off = 32; off; off >>= 1) acc[e] += __shfl_down(acc[e], off);
    __shared__ float sred[4][8];
    int wid = threadIdx.x >> 6;
    if ((threadIdx.x & 63) == 0) {
#pragma unroll
        for (int e = 0; e < 8; ++e) sred[wid][e] = acc[e];
    }
    __syncthreads();
    if (threadIdx.x == 0) {
        float lg[8], p[8];
        float mx = -1e30f;
        for (int e = 0; e < 8; ++e) {
            lg[e] = sred[0][e] + sred[1][e] + sred[2][e] + sred[3][e];
            mx = fmaxf(mx, lg[e]);
        }
        float sum = 0.f;
        for (int e = 0; e < 8; ++e) { p[e] = expf(lg[e] - mx); sum += p[e]; }
        for (int e = 0; e < 8; ++e) p[e] /= sum;
        int i1 = 0;
        for (int e = 1; e < 8; ++e) if (p[e] > p[i1]) i1 = e;
        int i2 = -1;
        for (int e = 0; e < 8; ++e) if (e != i1 && (i2 < 0 || p[e] > p[i2])) i2 = e;
        float wsum = p[i1] + p[i2];
        topi[n * 2] = i1; topi[n * 2 + 1] = i2;
        topw[n * 2] = p[i1] / wsum; topw[n * 2 + 1] = p[i2] / wsum;
        atomicAdd(&cnt[i1], 1); atomicAdd(&cnt[i2], 1);
        for (int e = 0; e < 8; ++e) atomicAdd(&psum[l * 8 + e], p[e]);
        atomicAdd(&fcnt[l * 8 + i1], 1.0f);
    }
}

__global__ void offsets_k(const int* __restrict__ cnt, int* __restrict__ basep,
                          int* __restrict__ fill, int* __restrict__ rowlist,
                          float* __restrict__ rowwt) {
    __shared__ int sbase[9];
    if (threadIdx.x == 0) {
        int b = 0;
        for (int e = 0; e < 8; ++e) { sbase[e] = b; b += (cnt[e] + 127) & ~127; }
        sbase[8] = b;
        for (int e = 0; e < 9; ++e) basep[e] = sbase[e];
    }
    __syncthreads();
    for (int e = 0; e < 8; ++e) {
        int c = cnt[e], rc = (c + 127) & ~127;
        for (int i = c + (int)threadIdx.x; i < rc; i += 256) {
            rowlist[sbase[e] + i] = -1;
            rowwt[sbase[e] + i] = 0.f;
        }
    }
    if (threadIdx.x < 8) fill[threadIdx.x] = 0;
}

__global__ void scatter_k(const int* __restrict__ topi, const float* __restrict__ topw,
                          const int* __restrict__ basep, int* __restrict__ fill,
                          int* __restrict__ rowlist, float* __restrict__ rowwt) {
    int n = blockIdx.x * 256 + threadIdx.x;
    if (n >= NTOK) return;
    for (int j = 0; j < 2; ++j) {
        int e = topi[n * 2 + j];
        int pos = atomicAdd(&fill[e], 1);
        rowlist[basep[e] + pos] = n;
        rowwt[basep[e] + pos] = topw[n * 2 + j];
    }
}

__global__ void colmean_k(const float* __restrict__ x, float* __restrict__ xm) {
    int d = blockIdx.x * 256 + threadIdx.x;
    if (d >= D) return;
    float s = 0.f;
    for (int n = 0; n < NTOK; ++n) s += x[(size_t)n * D + d];
    xm[d] = s / (float)NTOK;
}

__global__ void heads_k(const float* __restrict__ x0, const float* __restrict__ xm,
                        const float* __restrict__ tw, const float* __restrict__ tb,
                        const float* __restrict__ ew, const float* __restrict__ eb,
                        const float* __restrict__ psum, const float* __restrict__ fcnt,
                        float* __restrict__ out) {
    int t = threadIdx.x;
    if (t < 16) {
        float s = tb[t];
        for (int d = 0; d < D; ++d) s += x0[d] * tw[d * 16 + t];
        out[t] = s;
    } else if (t < 24) {
        int c = t - 16;
        float s = eb[c];
        for (int d = 0; d < D; ++d) s += xm[d] * ew[d * 8 + c];
        out[16 + c] = s;
    } else if (t == 24) {
        float aux = 0.f;
        for (int l = 0; l < 2; ++l) {
            float a = 0.f;
            for (int e = 0; e < 8; ++e)
                a += (fcnt[l * 8 + e] / (float)NTOK) * (psum[l * 8 + e] / (float)NTOK);
            aux += 8.f * a;
        }
        out[24] = aux;
    }
}

// ---------------- main GEMM ----------------
// C[M,N] = A[M,K] (bf16 hi/lo split) @ B[K,N] (fp32, split in staging)
// PREC: 1 = plain bf16 (hi only), 3 = bf16x3 split
// EXPERT: grid.y = e*16+mt with count/base bounding; GATHER: A rows via rowlist
// STORE: 0 = Cf[row*N+col]=v ; 1 = Cf += v ; 2 = atomicAdd(Cf[tok*N+col], v*wt)
//        3 = Chi/Clo[row*N+col] = split( silu(Cf[row*N+col]) * v )
template<int PREC, bool EXPERT, bool GATHER, int STORE>
__global__ __launch_bounds__(256) void k1_gemm(
    const u16* __restrict__ Ahi, const u16* __restrict__ Alo,
    const float* __restrict__ Ball, int K, int N,
    float* __restrict__ Cf, u16* __restrict__ Chi, u16* __restrict__ Clo,
    const int* __restrict__ rowlist, const float* __restrict__ rowwt,
    const int* __restrict__ cntp, const int* __restrict__ basep, int bstride) {
    int n0 = blockIdx.x * 128;
    int m0;
    const float* B = Ball;
    if constexpr (EXPERT) {
        int e = blockIdx.y >> 4;
        int mt = blockIdx.y & 15;
        if (mt * 128 >= cntp[e]) return;
        m0 = basep[e] + mt * 128;
        B = Ball + (size_t)e * (size_t)bstride;
    } else {
        m0 = blockIdx.y * 128;
    }

    __shared__ __align__(16) u16 As_hi[128][40];
    __shared__ __align__(16) u16 Bs_hi[128][40];
    __shared__ __align__(16) u16 As_lo[PREC == 3 ? 128 : 1][40];
    __shared__ __align__(16) u16 Bs_lo[PREC == 3 ? 128 : 1][40];

    int tid = threadIdx.x;
    int w = tid >> 6, lane = tid & 63;
    int wr = w >> 1, wc = w & 1;
    int l15 = lane & 15, l4 = lane >> 4;

    f32x4 acc[4][4];
#pragma unroll
    for (int i = 0; i < 4; ++i)
#pragma unroll
        for (int j = 0; j < 4; ++j) acc[i][j] = f32x4{0.f, 0.f, 0.f, 0.f};

    for (int k0 = 0; k0 < K; k0 += 32) {
        // stage A: 128 rows x 32 k (8-el segments)
        for (int s = tid; s < 512; s += 256) {
            int row = s >> 2, seg = s & 3;
            bool valid = true;
            size_t gofs = 0;
            if constexpr (GATHER) {
                int tok = rowlist[m0 + row];
                if (tok < 0) valid = false;
                else gofs = (size_t)tok * K + k0 + seg * 8;
            } else {
                gofs = (size_t)(m0 + row) * K + k0 + seg * 8;
            }
            if (valid) {
                *(int4*)&As_hi[row][seg * 8] = *(const int4*)(Ahi + gofs);
                if constexpr (PREC == 3)
                    *(int4*)&As_lo[row][seg * 8] = *(const int4*)(Alo + gofs);
            } else {
                *(int4*)&As_hi[row][seg * 8] = make_int4(0, 0, 0, 0);
                if constexpr (PREC == 3)
                    *(int4*)&As_lo[row][seg * 8] = make_int4(0, 0, 0, 0);
            }
        }
        // stage B transposed + split: 32 k-rows x 128 n
        for (int s = tid; s < 1024; s += 256) {
            int kr = s >> 5, nc = (s & 31) * 4;
            float4 bv = *(const float4*)(B + (size_t)(k0 + kr) * N + n0 + nc);
            float arr[4] = {bv.x, bv.y, bv.z, bv.w};
#pragma unroll
            for (int j = 0; j < 4; ++j) {
                u16 hi = f2bf(arr[j]);
                Bs_hi[nc + j][kr] = hi;
                if constexpr (PREC == 3) Bs_lo[nc + j][kr] = f2bf(arr[j] - bf2f(hi));
            }
        }
        __syncthreads();

        short8 ah[4], al[4], bh[4], bl[4];
#pragma unroll
        for (int mi = 0; mi < 4; ++mi) {
            ah[mi] = *(const short8*)&As_hi[wr * 64 + mi * 16 + l15][l4 * 8];
            if constexpr (PREC == 3) al[mi] = *(const short8*)&As_lo[wr * 64 + mi * 16 + l15][l4 * 8];
        }
#pragma unroll
        for (int nj = 0; nj < 4; ++nj) {
            bh[nj] = *(const short8*)&Bs_hi[wc * 64 + nj * 16 + l15][l4 * 8];
            if constexpr (PREC == 3) bl[nj] = *(const short8*)&Bs_lo[wc * 64 + nj * 16 + l15][l4 * 8];
        }
#pragma unroll
        for (int mi = 0; mi < 4; ++mi)
#pragma unroll
            for (int nj = 0; nj < 4; ++nj) {
                acc[mi][nj] = MFMA(ah[mi], bh[nj], acc[mi][nj]);
                if constexpr (PREC == 3) {
                    acc[mi][nj] = MFMA(ah[mi], bl[nj], acc[mi][nj]);
                    acc[mi][nj] = MFMA(al[mi], bh[nj], acc[mi][nj]);
                }
            }
        __syncthreads();
    }

#pragma unroll
    for (int mi = 0; mi < 4; ++mi)
#pragma unroll
        for (int nj = 0; nj < 4; ++nj)
#pragma unroll
            for (int r = 0; r < 4; ++r) {
                int row = m0 + wr * 64 + mi * 16 + l4 * 4 + r;
                int col = n0 + wc * 64 + nj * 16 + l15;
                float val = acc[mi][nj][r];
                if constexpr (STORE == 0) {
                    Cf[(size_t)row * N + col] = val;
                } else if constexpr (STORE == 1) {
                    Cf[(size_t)row * N + col] += val;
                } else if constexpr (STORE == 2) {
                    int tok = rowlist[row];
                    if (tok >= 0) atomicAdd(&Cf[(size_t)tok * N + col], val * rowwt[row]);
                } else {
                    float g = Cf[(size_t)row * N + col];
                    float o = g / (1.f + expf(-g)) * val;
                    u16 hh2 = f2bf(o);
                    Chi[(size_t)row * N + col] = hh2;
                    Clo[(size_t)row * N + col] = f2bf(o - bf2f(hh2));
                }
            }
}

// ---------------- flash attention (bf16x3, online softmax) ----------------
__global__ __launch_bounds__(256) void flash_k(
    const u16* __restrict__ qhi, const u16* __restrict__ qlo,
    const u16* __restrict__ khi, const u16* __restrict__ klo,
    const u16* __restrict__ vhi, const u16* __restrict__ vlo,
    u16* __restrict__ ahi, u16* __restrict__ alo) {
    int bx = blockIdx.x;
    int qt = bx & 3, hh = (bx >> 2) & 15, ch = bx >> 6;
    int q0 = qt * 128;
    int kvh = hh >> 2;
    int tid = threadIdx.x, w = tid >> 6, lane = tid & 63;
    int l15 = lane & 15, l4 = lane >> 4;

    __shared__ __align__(16) u16 Ks_hi[64][72], Ks_lo[64][72];
    __shared__ __align__(16) u16 Vt_hi[64][72], Vt_lo[64][72];
    __shared__ __align__(16) u16 Ps_hi[4][32][72], Ps_lo[4][32][72];

    short8 aqh[2][2], aql[2][2];
#pragma unroll
    for (int mi = 0; mi < 2; ++mi)
#pragma unroll
        for (int ks = 0; ks < 2; ++ks) {
            int tok = ch * CHUNK + q0 + w * 32 + mi * 16 + l15;
            size_t ofs = (size_t)tok * (NH * HD) + hh * HD + ks * 32 + l4 * 8;
            aqh[mi][ks] = *(const short8*)(qhi + ofs);
            aql[mi][ks] = *(const short8*)(qlo + ofs);
        }

    f32x4 accO[2][4];
    float m_[2][4], l_[2][4];
#pragma unroll
    for (int mi = 0; mi < 2; ++mi)
#pragma unroll
        for (int j = 0; j < 4; ++j) {
            accO[mi][j] = f32x4{0.f, 0.f, 0.f, 0.f};
            m_[mi][j] = -1e30f;
            l_[mi][j] = 0.f;
        }

    int jd = (q0 + 127) >> 6;
    for (int j = 0; j <= jd; ++j) {
        __syncthreads();
        for (int s = tid; s < 512; s += 256) {   // K tile: 64 rows x 8 segs of 8
            int kr = s >> 3, seg = s & 7;
            size_t ofs = (size_t)(ch * CHUNK + j * 64 + kr) * (KVH * HD) + kvh * HD + seg * 8;
            *(int4*)&Ks_hi[kr][seg * 8] = *(const int4*)(khi + ofs);
            *(int4*)&Ks_lo[kr][seg * 8] = *(const int4*)(klo + ofs);
        }
        {   // V tile transposed: each thread one (kr, 16-d seg)
            int kr = tid >> 2, seg = tid & 3;
            size_t ofs = (size_t)(ch * CHUNK + j * 64 + kr) * (KVH * HD) + kvh * HD + seg * 16;
            u16 th[16], tl[16];
            *(int4*)&th[0] = *(const int4*)(vhi + ofs);
            *(int4*)&th[8] = *(const int4*)(vhi + ofs + 8);
            *(int4*)&tl[0] = *(const int4*)(vlo + ofs);
            *(int4*)&tl[8] = *(const int4*)(vlo + ofs + 8);
#pragma unroll
            for (int d2 = 0; d2 < 16; ++d2) {
                Vt_hi[seg * 16 + d2][kr] = th[d2];
                Vt_lo[seg * 16 + d2][kr] = tl[d2];
            }
        }
        __syncthreads();

        f32x4 sf[2][4];
#pragma unroll
        for (int mi = 0; mi < 2; ++mi)
#pragma unroll
            for (int nj = 0; nj < 4; ++nj) {
                f32x4 c = f32x4{0.f, 0.f, 0.f, 0.f};
#pragma unroll
                for (int ks = 0; ks < 2; ++ks) {
                    short8 bh = *(const short8*)&Ks_hi[nj * 16 + l15][ks * 32 + l4 * 8];
                    short8 bl = *(const short8*)&Ks_lo[nj * 16 + l15][ks * 32 + l4 * 8];
                    c = MFMA(aqh[mi][ks], bh, c);
                    c = MFMA(aqh[mi][ks], bl, c);
                    c = MFMA(aql[mi][ks], bh, c);
                }
                sf[mi][nj] = c;
            }
        bool maskt = (j * 64 + 63) > q0;
#pragma unroll
        for (int mi = 0; mi < 2; ++mi)
#pragma unroll
            for (int nj = 0; nj < 4; ++nj)
#pragma unroll
                for (int r = 0; r < 4; ++r) {
                    float s = sf[mi][nj][r] * 0.125f;
                    if (maskt) {
                        int row = q0 + w * 32 + mi * 16 + l4 * 4 + r;
                        int col = j * 64 + nj * 16 + l15;
                        if (col > row) s = -1e30f;
                    }
                    sf[mi][nj][r] = s;
                }
#pragma unroll
        for (int mi = 0; mi < 2; ++mi) {
            float vsum[4], alpha[4];
#pragma unroll
            for (int r = 0; r < 4; ++r) {
                float v = fmaxf(fmaxf(sf[mi][0][r], sf[mi][1][r]),
                                fmaxf(sf[mi][2][r], sf[mi][3][r]));
#pragma unroll
                for (int off = 1; off < 16; off <<= 1) v = fmaxf(v, __shfl_xor(v, off));
                float mn = fmaxf(m_[mi][r], v);
                alpha[r] = expf(m_[mi][r] - mn);
                m_[mi][r] = mn;
                vsum[r] = 0.f;
            }
#pragma unroll
            for (int nj = 0; nj < 4; ++nj)
#pragma unroll
                for (int r = 0; r < 4; ++r) {
                    float pv = expf(sf[mi][nj][r] - m_[mi][r]);
                    vsum[r] += pv;
                    u16 ph = f2bf(pv);
                    Ps_hi[w][mi * 16 + l4 * 4 + r][nj * 16 + l15] = ph;
                    Ps_lo[w][mi * 16 + l4 * 4 + r][nj * 16 + l15] = f2bf(pv - bf2f(ph));
                }
#pragma unroll
            for (int r = 0; r < 4; ++r) {
                float v = vsum[r];
#pragma unroll
                for (int off = 1; off < 16; off <<= 1) v += __shfl_xor(v, off);
                l_[mi][r] = l_[mi][r] * alpha[r] + v;
#pragma unroll
                for (int dj = 0; dj < 4; ++dj) accO[mi][dj][r] *= alpha[r];
            }
        }
        // PV (same-wave LDS RAW; compiler inserts waits)
#pragma unroll
        for (int mi = 0; mi < 2; ++mi)
#pragma unroll
            for (int dj = 0; dj < 4; ++dj) {
                f32x4 c = accO[mi][dj];
#pragma unroll
                for (int ks = 0; ks < 2; ++ks) {
                    short8 pah = *(const short8*)&Ps_hi[w][mi * 16 + l15][ks * 32 + l4 * 8];
                    short8 pal = *(const short8*)&Ps_lo[w][mi * 16 + l15][ks * 32 + l4 * 8];
                    short8 vbh = *(const short8*)&Vt_hi[dj * 16 + l15][ks * 32 + l4 * 8];
                    short8 vbl = *(const short8*)&Vt_lo[dj * 16 + l15][ks * 32 + l4 * 8];
                    c = MFMA(pah, vbh, c);
                    c = MFMA(pah, vbl, c);
                    c = MFMA(pal, vbh, c);
                }
                accO[mi][dj] = c;
            }
    }

#pragma unroll
    for (int mi = 0; mi < 2; ++mi)
#pragma unroll
        for (int dj = 0; dj < 4; ++dj)
#pragma unroll
            for (int r = 0; r < 4; ++r) {
                int tok = ch * CHUNK + q0 + w * 32 + mi * 16 + l4 * 4 + r;
                int col = hh * HD + dj * 16 + l15;
                float o = accO[mi][dj][r] / l_[mi][r];
                u16 oh = f2bf(o);
                ahi[(size_t)tok * (NH * HD) + col] = oh;
                alo[(size_t)tok * (NH * HD) + col] = f2bf(o - bf2f(oh));
            }
}

// ---------------- launch ----------------

extern "C" void kernel_launch(void* const* d_in, const int* in_sizes, int n_in,
                              void* d_out, int out_size, void* d_ws, size_t ws_size,
                              hipStream_t stream) {
    const int*   ids  = (const int*)d_in[0];
    const float* embW = (const float*)d_in[1];
    const float* n1w  = (const float*)d_in[2];
    const float* n2w  = (const float*)d_in[3];
    const float* wq   = (const float*)d_in[4];
    const float* wk   = (const float*)d_in[5];
    const float* wv   = (const float*)d_in[6];
    const float* wo   = (const float*)d_in[7];
    const float* rw   = (const float*)d_in[8];
    const float* w1   = (const float*)d_in[9];
    const float* w3   = (const float*)d_in[10];
    const float* w2   = (const float*)d_in[11];
    const float* nfw  = (const float*)d_in[12];
    const float* lmw  = (const float*)d_in[13];
    const float* tw   = (const float*)d_in[14];
    const float* tb   = (const float*)d_in[15];
    const float* ew   = (const float*)d_in[16];
    const float* eb   = (const float*)d_in[17];
    float* out = (float*)d_out;

    char* p = (char*)d_ws;
    auto take = [&](size_t n) { char* r = p; p += (n + 255) & ~(size_t)255; return r; };
    float* h     = (float*)take((size_t)NTOK * D * 4);
    float* hnf   = (float*)take((size_t)NTOK * D * 4);
    u16*   hnhi  = (u16*)take((size_t)NTOK * D * 2);
    u16*   hnlo  = (u16*)take((size_t)NTOK * D * 2);
    float* qf    = (float*)take((size_t)NTOK * (NH * HD) * 4);
    float* kf    = (float*)take((size_t)NTOK * (KVH * HD) * 4);
    float* vf    = (float*)take((size_t)NTOK * (KVH * HD) * 4);
    u16*   qhi   = (u16*)take((size_t)NTOK * (NH * HD) * 2);
    u16*   qlo   = (u16*)take((size_t)NTOK * (NH * HD) * 2);
    u16*   khi   = (u16*)take((size_t)NTOK * (KVH * HD) * 2);
    u16*   klo   = (u16*)take((size_t)NTOK * (KVH * HD) * 2);
    u16*   vhi   = (u16*)take((size_t)NTOK * (KVH * HD) * 2);
    u16*   vlo   = (u16*)take((size_t)NTOK * (KVH * HD) * 2);
    u16*   atthi = (u16*)take((size_t)NTOK * D * 2);
    u16*   attlo = (u16*)take((size_t)NTOK * D * 2);
    float* u1    = (float*)take((size_t)TCAP * FF * 4);
    u16*   thi   = (u16*)take((size_t)TCAP * FF * 2);
    u16*   tlo   = (u16*)take((size_t)TCAP * FF * 2);
    float* ct    = (float*)take((size_t)CHUNK * 32 * 4);
    float* st    = (float*)take((size_t)CHUNK * 32 * 4);
    float* xm    = (float*)take((size_t)D * 4);
    int*   topi  = (int*)take((size_t)NTOK * 2 * 4);
    float* topw  = (float*)take((size_t)NTOK * 2 * 4);
    int*   cnt   = (int*)take(8 * 4);
    int*   fill  = (int*)take(8 * 4);
    int*   basep = (int*)take(9 * 4);
    int*   rowlist = (int*)take((size_t)TCAP * 4);
    float* rowwt   = (float*)take((size_t)TCAP * 4);
    float* stats   = (float*)take(32 * 4);  // psum[2][8] then fcnt[2][8]
    float* psum = stats;
    float* fcnt = stats + 16;

    ropetab_k<<<64, 256, 0, stream>>>(ct, st);
    embed_k<<<NTOK, 256, 0, stream>>>(ids, embW, h);
    zero32_k<<<1, 64, 0, stream>>>((u32*)stats, 32);

    for (int l = 0; l < 2; ++l) {
        rmsnorm_k<<<NTOK, 256, 0, stream>>>(h, n1w + (size_t)l * D, hnf, hnhi, hnlo);
        k1_gemm<3, false, false, 0><<<dim3(8, 16), 256, 0, stream>>>(
            hnhi, hnlo, wq + (size_t)l * D * (NH * HD), D, NH * HD, qf,
            nullptr, nullptr, nullptr, nullptr, nullptr, nullptr, 0);
        k1_gemm<3, false, false, 0><<<dim3(2, 16), 256, 0, stream>>>(
            hnhi, hnlo, wk + (size_t)l * D * (KVH * HD), D, KVH * HD, kf,
            nullptr, nullptr, nullptr, nullptr, nullptr, nullptr, 0);
        k1_gemm<3, false, false, 0><<<dim3(2, 16), 256, 0, stream>>>(
            hnhi, hnlo, wv + (size_t)l * D * (KVH * HD), D, KVH * HD, vf,
            nullptr, nullptr, nullptr, nullptr, nullptr, nullptr, 0);
        rope_k<<<NTOK, 256, 0, stream>>>(qf, kf, vf, ct, st, qhi, qlo, khi, klo, vhi, vlo);
        flash_k<<<256, 256, 0, stream>>>(qhi, qlo, khi, klo, vhi, vlo, atthi, attlo);
        k1_gemm<3, false, false, 1><<<dim3(8, 16), 256, 0, stream>>>(
            atthi, attlo, wo + (size_t)l * (NH * HD) * D, NH * HD, D, h,
            nullptr, nullptr, nullptr, nullptr, nullptr, nullptr, 0);

        rmsnorm_k<<<NTOK, 256, 0, stream>>>(h, n2w + (size_t)l * D, hnf, hnhi, hnlo);
        zero32_k<<<1, 64, 0, stream>>>((u32*)cnt, 8);
        router_k<<<NTOK, 256, 0, stream>>>(hnf, rw + (size_t)l * D * NE, l, topi, topw, cnt, psum, fcnt);
        offsets_k<<<1, 256, 0, stream>>>(cnt, basep, fill, rowlist, rowwt);
        scatter_k<<<8, 256, 0, stream>>>(topi, topw, basep, fill, rowlist, rowwt);
        k1_gemm<3, true, true, 0><<<dim3(16, 128), 256, 0, stream>>>(
            hnhi, hnlo, w1 + (size_t)l * NE * D * FF, D, FF, u1,
            nullptr, nullptr, rowlist, rowwt, cnt, basep, D * FF);
        k1_gemm<3, true, true, 3><<<dim3(16, 128), 256, 0, stream>>>(
            hnhi, hnlo, w3 + (size_t)l * NE * D * FF, D, FF, u1,
            thi, tlo, rowlist, rowwt, cnt, basep, D * FF);
        k1_gemm<3, true, false, 2><<<dim3(8, 128), 256, 0, stream>>>(
            thi, tlo, w2 + (size_t)l * NE * FF * D, FF, D, h,
            nullptr, nullptr, rowlist, rowwt, cnt, basep, FF * D);
    }

    rmsnorm_k<<<NTOK, 256, 0, stream>>>(h, nfw, hnf, hnhi, hnlo);
    k1_gemm<1, false, false, 0><<<dim3(VOC / 128, 16), 256, 0, stream>>>(
        hnhi, nullptr, lmw, D, VOC, out,
        nullptr, nullptr, nullptr, nullptr, nullptr, nullptr, 0);
    colmean_k<<<4, 256, 0, stream>>>(hnf, xm);
    heads_k<<<1, 64, 0, stream>>>(hnf, xm, tw, tb, ew, eb, psum, fcnt,
                                  out + (size_t)NTOK * VOC);
}